// Round 2
// baseline (943.633 us; speedup 1.0000x reference)
//
#include <hip/hip_runtime.h>
#include <hip/hip_bf16.h>

#define DIMD 2048
#define NHD 16
#define QLORA 1536
#define KVLORA 512
#define NOPED 128
#define ROPED 64
#define VDIMD 128
#define QKD 192
#define BBD 2
#define SSD 2048
#define BSD (BBD*SSD)       // 4096 tokens
#define KVPAD 640           // 576 padded to multiple of 128
#define BHN (BBD*NHD)       // 32 (b,h) pairs
#define EPSF 1.1920929e-07f
#define SCALEF 0.07216878364870322f  // 192^-0.5

typedef __hip_bfloat16 bf16;
typedef __attribute__((ext_vector_type(8))) short short8;
typedef __attribute__((ext_vector_type(4))) float floatx4;

typedef __attribute__((address_space(1))) char as1_char;
typedef __attribute__((address_space(3))) char as3_char;
#define GLD16(g, l) __builtin_amdgcn_global_load_lds((as1_char*)(g), (as3_char*)(l), 16, 0, 0)

// ---------------- block reductions (256 threads = 4 waves) ----------------
__device__ __forceinline__ float block_sum(float x) {
#pragma unroll
  for (int o = 32; o > 0; o >>= 1) x += __shfl_xor(x, o, 64);
  __shared__ float red[4];
  __syncthreads();
  if ((threadIdx.x & 63) == 0) red[threadIdx.x >> 6] = x;
  __syncthreads();
  return red[0] + red[1] + red[2] + red[3];
}

__device__ __forceinline__ float block_max(float x) {
#pragma unroll
  for (int o = 32; o > 0; o >>= 1) x = fmaxf(x, __shfl_xor(x, o, 64));
  __shared__ float redm[4];
  __syncthreads();
  if ((threadIdx.x & 63) == 0) redm[threadIdx.x >> 6] = x;
  __syncthreads();
  return fmaxf(fmaxf(redm[0], redm[1]), fmaxf(redm[2], redm[3]));
}

// ---------------- generic bf16 MFMA GEMM:  C = A(MxK) * B(NxK)^T + bias ----------------
// m97 structure: 128x128 tile, BK=32, 4 waves each 64x64 via 4x4 mfma_f32_16x16x32_bf16,
// global_load_lds width-16 staging (lane-contiguous LDS, unpadded).
template<bool STORE_BF16, bool CAUSAL>
__global__ __launch_bounds__(256)
void gemm_bt(const bf16* __restrict__ A, const bf16* __restrict__ Bm,
             const float* __restrict__ bias, void* __restrict__ Cp,
             int M, int N, int K, long sA, long sB, long sC, int ldc)
{
  int m0 = blockIdx.y * 128, n0 = blockIdx.x * 128;
  if (CAUSAL && n0 > m0) return;  // tile entirely above diagonal
  long z = blockIdx.z;
  A  += z * sA;
  Bm += z * sB;

  __shared__ __align__(16) bf16 Asm[128 * 32];
  __shared__ __align__(16) bf16 Bsm[128 * 32];

  const int tid  = threadIdx.x;
  const int lane = tid & 63;
  const int wv   = tid >> 6;        // wave 0..3
  const int wm   = (wv >> 1) << 6;  // wave row offset (0/64)
  const int wn   = (wv & 1) << 6;   // wave col offset (0/64)
  const int fr   = lane & 15;       // fragment row (m or n)
  const int q8   = (lane >> 4) << 3;// k-offset within fragment

  floatx4 acc[4][4];
#pragma unroll
  for (int i = 0; i < 4; ++i)
#pragma unroll
    for (int j = 0; j < 4; ++j)
      acc[i][j] = (floatx4){0.f, 0.f, 0.f, 0.f};

  for (int k0 = 0; k0 < K; k0 += 32) {
    __syncthreads();  // previous iter's LDS reads done
#pragma unroll
    for (int it = 0; it < 2; ++it) {
      int seg = it * 256 + tid;       // 512 16B segments per tile
      int row = seg >> 2, cs = seg & 3;
      GLD16(A  + (long)(m0 + row) * K + k0 + cs * 8, &Asm[(it * 256 + wv * 64) * 8]);
      GLD16(Bm + (long)(n0 + row) * K + k0 + cs * 8, &Bsm[(it * 256 + wv * 64) * 8]);
    }
    __syncthreads();  // drains vmcnt (global_load_lds) per barrier semantics

    short8 fa[4], fb[4];
#pragma unroll
    for (int t = 0; t < 4; ++t) fa[t] = *(const short8*)&Asm[(wm + t * 16 + fr) * 32 + q8];
#pragma unroll
    for (int t = 0; t < 4; ++t) fb[t] = *(const short8*)&Bsm[(wn + t * 16 + fr) * 32 + q8];
#pragma unroll
    for (int i = 0; i < 4; ++i)
#pragma unroll
      for (int j = 0; j < 4; ++j)
        acc[i][j] = __builtin_amdgcn_mfma_f32_16x16x32_bf16(fa[i], fb[j], acc[i][j], 0, 0, 0);
  }

  // epilogue: C/D layout col=lane&15, row=(lane>>4)*4+reg (verified m89/m91)
  long cb = z * sC;
  int rq = (lane >> 4) * 4;
#pragma unroll
  for (int i = 0; i < 4; ++i) {
#pragma unroll
    for (int j = 0; j < 4; ++j) {
      int col = n0 + wn + j * 16 + fr;
      float bv = bias ? bias[col] : 0.f;
#pragma unroll
      for (int r = 0; r < 4; ++r) {
        int rowg = m0 + wm + i * 16 + rq + r;
        float v = acc[i][j][r] + bv;
        if (STORE_BF16)
          ((bf16*)Cp)[cb + (long)rowg * ldc + col] = __float2bfloat16(v);
        else
          ((float*)Cp)[cb + (long)rowg * ldc + col] = v;
      }
    }
  }
}

// ---------------- fp32 -> bf16 convert (optional zero row-padding) ----------------
__global__ void cvt_pad(const float* __restrict__ src, bf16* __restrict__ dst,
                        int srcRows, int dstRows, int cols)
{
  long n = (long)dstRows * cols;
  long i = (long)blockIdx.x * 256 + threadIdx.x;
  if (i >= n) return;
  if (srcRows == dstRows) { dst[i] = __float2bfloat16(src[i]); return; }
  long r = i / cols, c = i - r * cols;
  dst[i] = __float2bfloat16(r < (long)srcRows ? src[r * cols + c] : 0.f);
}

// ---------------- rmsnorm (row per block), bf16 in (+opt fp32 bias), bf16 out ----------------
template<int L>
__global__ __launch_bounds__(256)
void rmsnorm_k(const bf16* __restrict__ in, const float* __restrict__ bias,
               const float* __restrict__ w, bf16* __restrict__ out, int ldin)
{
  constexpr int NIT = L / 256;
  long r = blockIdx.x;
  const bf16* row = in + r * ldin;
  int tid = threadIdx.x;
  float v[NIT];
  float ss = 0.f;
#pragma unroll
  for (int i = 0; i < NIT; ++i) {
    int c = tid + (i << 8);
    float x = __bfloat162float(row[c]) + (bias ? bias[c] : 0.f);
    v[i] = x;
    ss += x * x;
  }
  ss = block_sum(ss);
  float sc = rsqrtf(ss / (float)L + EPSF);
#pragma unroll
  for (int i = 0; i < NIT; ++i) {
    int c = tid + (i << 8);
    out[r * L + c] = __float2bfloat16(v[i] * sc * w[c]);
  }
}

// ---------------- build Q (rope on last 64) -> (B,NH,S,192) bf16 ----------------
__global__ void build_q(const bf16* __restrict__ Qf, const float* __restrict__ freqs,
                        bf16* __restrict__ Qh)
{
  int idx = blockIdx.x * 256 + threadIdx.x;
  if (idx >= BSD * NHD * 96) return;
  int j = idx % 96;
  int h = (idx / 96) % NHD;
  int srow = idx / (96 * NHD);
  int s = srow & (SSD - 1);
  int b = srow >> 11;
  const bf16* src = Qf + (long)srow * (NHD * QKD) + h * QKD + 2 * j;
  float x0 = __bfloat162float(src[0]), x1 = __bfloat162float(src[1]), y0, y1;
  if (j >= 64) {
    int i = j - 64;
    float f = freqs[s * 32 + i];
    float c = cosf(f), sn = sinf(f);
    y0 = x0 * c - x1 * sn;
    y1 = x0 * sn + x1 * c;
  } else { y0 = x0; y1 = x1; }
  bf16* dst = Qh + ((long)(b * NHD + h) * SSD + s) * QKD + 2 * j;
  dst[0] = __float2bfloat16(y0);
  dst[1] = __float2bfloat16(y1);
}

// ---------------- build K = [K_nope | rope(K_rope) bcast] -> (B,NH,S,192) bf16 ----------------
__global__ void build_k(const bf16* __restrict__ kvf, const bf16* __restrict__ kvkr,
                        const float* __restrict__ kvb, const float* __restrict__ freqs,
                        bf16* __restrict__ Kh)
{
  int idx = blockIdx.x * 256 + threadIdx.x;
  if (idx >= BSD * NHD * 96) return;
  int j = idx % 96;
  int h = (idx / 96) % NHD;
  int srow = idx / (96 * NHD);
  int s = srow & (SSD - 1);
  int b = srow >> 11;
  float y0, y1;
  if (j < 64) {
    const bf16* src = kvf + (long)srow * 4096 + h * 256 + 2 * j;
    y0 = __bfloat162float(src[0]); y1 = __bfloat162float(src[1]);
  } else {
    int i = j - 64;
    float x0 = __bfloat162float(kvkr[(long)srow * KVPAD + 512 + 2 * i]) + kvb[512 + 2 * i];
    float x1 = __bfloat162float(kvkr[(long)srow * KVPAD + 513 + 2 * i]) + kvb[513 + 2 * i];
    float f = freqs[s * 32 + i];
    float c = cosf(f), sn = sinf(f);
    y0 = x0 * c - x1 * sn;
    y1 = x0 * sn + x1 * c;
  }
  bf16* dst = Kh + ((long)(b * NHD + h) * SSD + s) * QKD + 2 * j;
  dst[0] = __float2bfloat16(y0);
  dst[1] = __float2bfloat16(y1);
}

// ---------------- build V^T: kv(B,S,NH,256)[...,128:256] -> Vt (BH,128,S) bf16 ----------------
__global__ __launch_bounds__(256)
void build_vt(const bf16* __restrict__ kvf, bf16* __restrict__ Vt)
{
  __shared__ float t[32][33];
  int s0 = blockIdx.x * 32, d0 = blockIdx.y * 32, z = blockIdx.z;
  int b = z / NHD, h = z % NHD;
  int tx = threadIdx.x, ty = threadIdx.y;  // 32 x 8
#pragma unroll
  for (int r = 0; r < 4; ++r) {
    int sl = ty + r * 8;
    t[sl][tx] = __bfloat162float(kvf[(long)(b * SSD + s0 + sl) * 4096 + h * 256 + 128 + d0 + tx]);
  }
  __syncthreads();
#pragma unroll
  for (int r = 0; r < 4; ++r) {
    int dl = ty + r * 8;
    Vt[((long)z * 128 + d0 + dl) * SSD + s0 + tx] = __float2bfloat16(t[tx][dl]);
  }
}

// ---------------- causal scale+softmax over bf16 scores, in place ----------------
__global__ __launch_bounds__(256)
void softmax_causal(bf16* __restrict__ Sc)
{
  int q = blockIdx.x;
  long z = blockIdx.y;
  bf16* row = Sc + (z * SSD + q) * (long)SSD;
  int tid = threadIdx.x;
  float v[8];
  float mx = -1e30f;
#pragma unroll
  for (int i = 0; i < 8; ++i) {
    int k = tid + (i << 8);
    if (k <= q) {
      float x = SCALEF * __bfloat162float(row[k]);
      v[i] = x;
      mx = fmaxf(mx, x);
    } else v[i] = -1e30f;
  }
  mx = block_max(mx);
  float s = 0.f;
#pragma unroll
  for (int i = 0; i < 8; ++i) {
    float e = (v[i] > -1e29f) ? expf(v[i] - mx) : 0.f;
    v[i] = e;
    s += e;
  }
  s = block_sum(s);
  float inv = 1.f / s;
#pragma unroll
  for (int i = 0; i < 8; ++i) {
    int k = tid + (i << 8);
    row[k] = __float2bfloat16(v[i] * inv);  // zeros for k>q overwrite skipped-tile garbage
  }
}

// ---------------- reorder attn (BH,S,128) -> (B,S,NH*128) bf16 ----------------
__global__ void reorder_attn(const bf16* __restrict__ in, bf16* __restrict__ out)
{
  long idx = (long)blockIdx.x * 256 + threadIdx.x;
  if (idx >= (long)BHN * SSD * 128) return;
  int d = (int)(idx & 127);
  long t = idx >> 7;
  int s = (int)(t & (SSD - 1));
  int z = (int)(t >> 11);
  int b = z / NHD, h = z % NHD;
  out[((long)(b * SSD + s) * NHD + h) * 128 + d] = in[idx];
}

// ---------------- diagnostic: ws too small even for chunk=1 ----------------
__global__ void diag_fill(float* out) { out[blockIdx.x * 256 + threadIdx.x] = 1000.0f; }

extern "C" void kernel_launch(void* const* d_in, const int* in_sizes, int n_in,
                              void* d_out, int out_size, void* d_ws, size_t ws_size,
                              hipStream_t stream)
{
  const float* x     = (const float*)d_in[0];
  const float* freqs = (const float*)d_in[1];
  // d_in[2] causal_mask: causality implemented directly
  const float* Wqd   = (const float*)d_in[3];
  const float* Wqdb  = (const float*)d_in[4];
  const float* qnw   = (const float*)d_in[5];
  const float* Wqu   = (const float*)d_in[6];
  const float* Wqub  = (const float*)d_in[7];
  const float* Wkvd  = (const float*)d_in[8];
  const float* Wkvdb = (const float*)d_in[9];
  const float* kvnw  = (const float*)d_in[10];
  const float* Wkvu  = (const float*)d_in[11];
  const float* Wkvub = (const float*)d_in[12];
  const float* Wo    = (const float*)d_in[13];
  const float* Wob   = (const float*)d_in[14];
  float* out = (float*)d_out;

  char* ws = (char*)d_ws;
  size_t off = 0;
  auto alloc = [&](size_t bytes) {
    void* p = ws + off;
    off += (bytes + 255) & ~(size_t)255;
    return p;
  };

  // --- persistent / aliased regions (all bf16 intermediates) ---
  bf16* Wqd16  = (bf16*)alloc((size_t)QLORA * DIMD * 2);        // dead after GEMM1
  bf16* Wqu16  = (bf16*)alloc((size_t)3072 * QLORA * 2);        // dead after GEMM2
  bf16* Wkvd16 = (bf16*)alloc((size_t)KVPAD * DIMD * 2);        // dead after GEMM3
  bf16* Wkvu16 = (bf16*)alloc((size_t)4096 * KVLORA * 2);       // dead after GEMM4
  bf16* Wo16   = (bf16*)alloc((size_t)DIMD * 2048 * 2);         // live till final GEMM
  bf16* x16    = (bf16*)alloc((size_t)BSD * DIMD * 2);          // dead after GEMM3; reused as attnbh
  bf16* Ra     = (bf16*)alloc((size_t)BSD * QLORA * 2);         // qdown, then kvkr
  bf16* Rb     = (bf16*)alloc((size_t)BSD * QLORA * 2);         // qlat, then kvlat
  bf16* Rc     = (bf16*)alloc((size_t)BSD * 4096 * 2);          // Qf, then kvf, then attnall
  bf16* Qh16   = (bf16*)alloc((size_t)BHN * SSD * QKD * 2);
  bf16* Kh16   = (bf16*)alloc((size_t)BHN * SSD * QKD * 2);
  bf16* Vt16   = (bf16*)alloc((size_t)BHN * 128 * SSD * 2);

  bf16* qdown   = Ra;  bf16* kvkr    = Ra;
  bf16* qlat16  = Rb;  bf16* kvlat16 = Rb;
  bf16* Qf      = Rc;  bf16* kvf     = Rc;  bf16* attnall = Rc;
  bf16* attnbh  = x16;

  size_t fixed = off;
  int chunk = 0;
  for (int c = 8; c >= 1; c >>= 1)
    if (fixed + (size_t)c * SSD * SSD * 2 <= ws_size) { chunk = c; break; }
  if (!chunk) { diag_fill<<<8, 256, 0, stream>>>(out); return; }
  bf16* Sc16 = (bf16*)alloc((size_t)chunk * SSD * SSD * 2);

  dim3 blk(256);
  auto cdiv = [](long a, long b) { return (int)((a + b - 1) / b); };

  // --- converts to bf16 ---
  cvt_pad<<<cdiv((long)BSD * DIMD, 256), blk, 0, stream>>>(x, x16, 1, 1, BSD * DIMD);
  cvt_pad<<<cdiv((long)QLORA * DIMD, 256), blk, 0, stream>>>(Wqd, Wqd16, 1, 1, QLORA * DIMD);
  cvt_pad<<<cdiv((long)3072 * QLORA, 256), blk, 0, stream>>>(Wqu, Wqu16, 1, 1, 3072 * QLORA);
  cvt_pad<<<cdiv((long)KVPAD * DIMD, 256), blk, 0, stream>>>(Wkvd, Wkvd16, 576, KVPAD, DIMD);
  cvt_pad<<<cdiv((long)4096 * KVLORA, 256), blk, 0, stream>>>(Wkvu, Wkvu16, 1, 1, 4096 * KVLORA);
  cvt_pad<<<cdiv((long)DIMD * 2048, 256), blk, 0, stream>>>(Wo, Wo16, 1, 1, DIMD * 2048);

  // --- Q path ---
  gemm_bt<true, false><<<dim3(QLORA / 128, BSD / 128, 1), blk, 0, stream>>>(
      x16, Wqd16, Wqdb, qdown, BSD, QLORA, DIMD, 0, 0, 0, QLORA);
  rmsnorm_k<QLORA><<<BSD, blk, 0, stream>>>(qdown, nullptr, qnw, qlat16, QLORA);
  gemm_bt<true, false><<<dim3(3072 / 128, BSD / 128, 1), blk, 0, stream>>>(
      qlat16, Wqu16, Wqub, Qf, BSD, 3072, QLORA, 0, 0, 0, 3072);
  build_q<<<cdiv((long)BSD * NHD * 96, 256), blk, 0, stream>>>(Qf, freqs, Qh16);

  // --- KV path ---
  gemm_bt<true, false><<<dim3(KVPAD / 128, BSD / 128, 1), blk, 0, stream>>>(
      x16, Wkvd16, nullptr, kvkr, BSD, KVPAD, DIMD, 0, 0, 0, KVPAD);
  rmsnorm_k<KVLORA><<<BSD, blk, 0, stream>>>(kvkr, Wkvdb, kvnw, kvlat16, KVPAD);
  gemm_bt<true, false><<<dim3(4096 / 128, BSD / 128, 1), blk, 0, stream>>>(
      kvlat16, Wkvu16, Wkvub, kvf, BSD, 4096, KVLORA, 0, 0, 0, 4096);
  build_k<<<cdiv((long)BSD * NHD * 96, 256), blk, 0, stream>>>(kvf, kvkr, Wkvdb, freqs, Kh16);
  build_vt<<<dim3(SSD / 32, 128 / 32, BHN), dim3(32, 8), 0, stream>>>(kvf, Vt16);

  // --- attention, chunked over (b,h) to bound the scores buffer ---
  for (int c0 = 0; c0 < BHN; c0 += chunk) {
    gemm_bt<true, true><<<dim3(SSD / 128, SSD / 128, chunk), blk, 0, stream>>>(
        Qh16 + (long)c0 * SSD * QKD, Kh16 + (long)c0 * SSD * QKD, nullptr, Sc16,
        SSD, SSD, QKD, (long)SSD * QKD, (long)SSD * QKD, (long)SSD * SSD, SSD);
    softmax_causal<<<dim3(SSD, chunk), blk, 0, stream>>>(Sc16);
    gemm_bt<true, false><<<dim3(1, SSD / 128, chunk), blk, 0, stream>>>(
        Sc16, Vt16 + (long)c0 * 128 * SSD, nullptr, attnbh + (long)c0 * SSD * 128,
        SSD, 128, SSD, (long)SSD * SSD, (long)128 * SSD, (long)SSD * 128, 128);
  }
  reorder_attn<<<cdiv((long)BHN * SSD * 128, 256), blk, 0, stream>>>(attnbh, attnall);

  // --- output projection (fp32 out) ---
  gemm_bt<false, false><<<dim3(2048 / 128, BSD / 128, 1), blk, 0, stream>>>(
      attnall, Wo16, Wob, out, BSD, DIMD, 2048, 0, 0, 0, DIMD);
}

// Round 3
// 647.633 us; speedup vs baseline: 1.4570x; 1.4570x over previous
//
#include <hip/hip_runtime.h>
#include <hip/hip_bf16.h>

#define DIMD 2048
#define NHD 16
#define QLORA 1536
#define KVLORA 512
#define QKD 192
#define BBD 2
#define SSD 2048
#define BSD (BBD*SSD)       // 4096 tokens
#define KVPAD 640           // 576 padded to multiple of 128
#define BHN (BBD*NHD)       // 32 (b,h) pairs
#define EPSF 1.1920929e-07f
#define SCALEF 0.07216878364870322f  // 192^-0.5

typedef __hip_bfloat16 bf16;
typedef __attribute__((ext_vector_type(8))) short short8;
typedef __attribute__((ext_vector_type(4))) float floatx4;

typedef __attribute__((address_space(1))) char as1_char;
typedef __attribute__((address_space(3))) char as3_char;
#define GLD16(g, l) __builtin_amdgcn_global_load_lds((as1_char*)(g), (as3_char*)(l), 16, 0, 0)

// ---------------- block reduction (256 threads = 4 waves) ----------------
__device__ __forceinline__ float block_sum(float x) {
#pragma unroll
  for (int o = 32; o > 0; o >>= 1) x += __shfl_xor(x, o, 64);
  __shared__ float red[4];
  __syncthreads();
  if ((threadIdx.x & 63) == 0) red[threadIdx.x >> 6] = x;
  __syncthreads();
  return red[0] + red[1] + red[2] + red[3];
}

// ---------------- generic bf16 MFMA GEMM:  C = A(MxK) * B(NxK)^T + bias ----------------
template<bool STORE_BF16>
__global__ __launch_bounds__(256)
void gemm_bt(const bf16* __restrict__ A, const bf16* __restrict__ Bm,
             const float* __restrict__ bias, void* __restrict__ Cp,
             int M, int N, int K, long sA, long sB, long sC, int ldc)
{
  int m0 = blockIdx.y * 128, n0 = blockIdx.x * 128;
  long z = blockIdx.z;
  A  += z * sA;
  Bm += z * sB;

  __shared__ __align__(16) bf16 Asm[128 * 32];
  __shared__ __align__(16) bf16 Bsm[128 * 32];

  const int tid  = threadIdx.x;
  const int lane = tid & 63;
  const int wv   = tid >> 6;
  const int wm   = (wv >> 1) << 6;
  const int wn   = (wv & 1) << 6;
  const int fr   = lane & 15;
  const int q8   = (lane >> 4) << 3;

  floatx4 acc[4][4];
#pragma unroll
  for (int i = 0; i < 4; ++i)
#pragma unroll
    for (int j = 0; j < 4; ++j)
      acc[i][j] = (floatx4){0.f, 0.f, 0.f, 0.f};

  for (int k0 = 0; k0 < K; k0 += 32) {
    __syncthreads();
#pragma unroll
    for (int it = 0; it < 2; ++it) {
      int seg = it * 256 + tid;
      int row = seg >> 2, cs = seg & 3;
      GLD16(A  + (long)(m0 + row) * K + k0 + cs * 8, &Asm[(it * 256 + wv * 64) * 8]);
      GLD16(Bm + (long)(n0 + row) * K + k0 + cs * 8, &Bsm[(it * 256 + wv * 64) * 8]);
    }
    __syncthreads();

    short8 fa[4], fb[4];
#pragma unroll
    for (int t = 0; t < 4; ++t) fa[t] = *(const short8*)&Asm[(wm + t * 16 + fr) * 32 + q8];
#pragma unroll
    for (int t = 0; t < 4; ++t) fb[t] = *(const short8*)&Bsm[(wn + t * 16 + fr) * 32 + q8];
#pragma unroll
    for (int i = 0; i < 4; ++i)
#pragma unroll
      for (int j = 0; j < 4; ++j)
        acc[i][j] = __builtin_amdgcn_mfma_f32_16x16x32_bf16(fa[i], fb[j], acc[i][j], 0, 0, 0);
  }

  long cb = z * sC;
  int rq = (lane >> 4) * 4;
#pragma unroll
  for (int i = 0; i < 4; ++i) {
#pragma unroll
    for (int j = 0; j < 4; ++j) {
      int col = n0 + wn + j * 16 + fr;
      float bv = bias ? bias[col] : 0.f;
#pragma unroll
      for (int r = 0; r < 4; ++r) {
        int rowg = m0 + wm + i * 16 + rq + r;
        float v = acc[i][j][r] + bv;
        if (STORE_BF16)
          ((bf16*)Cp)[cb + (long)rowg * ldc + col] = __float2bfloat16(v);
        else
          ((float*)Cp)[cb + (long)rowg * ldc + col] = v;
      }
    }
  }
}

// ---------------- fused flash attention (causal), one head x one 128-row Q tile ----------------
// Q frags in regs; K(48KB)/Vt(32KB) staged via global_load_lds; P through LDS (aliases K).
__global__ __launch_bounds__(256, 2)
void flash_attn(const bf16* __restrict__ Qh, const bf16* __restrict__ Kh,
                const bf16* __restrict__ Vt, bf16* __restrict__ attnall)
{
  const int qt = (int)gridDim.x - 1 - blockIdx.x;  // heavy (long) tiles dispatch first
  const int z  = blockIdx.y;                       // b*NH + h
  const int b = z >> 4, h = z & 15;
  const int q0 = qt * 128;

  const bf16* Qg = Qh + (long)z * SSD * QKD;
  const bf16* Kg = Kh + (long)z * SSD * QKD;
  const bf16* Vg = Vt + (long)z * 128 * SSD;

  __shared__ __align__(16) bf16 Ksm[6 * 128 * 32];  // 48KB; P aliases first 32KB
  __shared__ __align__(16) bf16 Vsm[4 * 128 * 32];  // 32KB
  bf16* Psm = Ksm;

  const int tid = threadIdx.x;
  const int lane = tid & 63;
  const int wv = tid >> 6;
  const int fr = lane & 15;
  const int g4 = lane >> 4;
  const int q8 = g4 << 3;
  const int wrow = wv * 32;   // wave owns q-rows [wrow, wrow+32)

  // --- Q fragments into registers (staged through Ksm) ---
  short8 qf[2][6];
#pragma unroll
  for (int c = 0; c < 6; ++c)
#pragma unroll
    for (int it = 0; it < 2; ++it) {
      int seg = it * 256 + tid;
      int row = seg >> 2, cs = seg & 3;
      GLD16(Qg + (long)(q0 + row) * QKD + c * 32 + cs * 8,
            &Ksm[c * 4096 + (it * 256 + wv * 64) * 8]);
    }
  __syncthreads();
#pragma unroll
  for (int i = 0; i < 2; ++i)
#pragma unroll
    for (int c = 0; c < 6; ++c)
      qf[i][c] = *(const short8*)&Ksm[c * 4096 + (wrow + i * 16 + fr) * 32 + q8];

  floatx4 oacc[2][8];
#pragma unroll
  for (int i = 0; i < 2; ++i)
#pragma unroll
    for (int n = 0; n < 8; ++n)
      oacc[i][n] = (floatx4){0.f, 0.f, 0.f, 0.f};
  float mi[2][4], li[2][4];
#pragma unroll
  for (int i = 0; i < 2; ++i)
#pragma unroll
    for (int r = 0; r < 4; ++r) { mi[i][r] = -1e30f; li[i][r] = 0.f; }

  for (int j = 0; j <= qt; ++j) {
    const int jb = j * 128;
    __syncthreads();  // qf reads / prev-iter P & V reads complete before restaging
#pragma unroll
    for (int c = 0; c < 6; ++c)
#pragma unroll
      for (int it = 0; it < 2; ++it) {
        int seg = it * 256 + tid;
        int row = seg >> 2, cs = seg & 3;
        GLD16(Kg + (long)(jb + row) * QKD + c * 32 + cs * 8,
              &Ksm[c * 4096 + (it * 256 + wv * 64) * 8]);
      }
#pragma unroll
    for (int c = 0; c < 4; ++c)
#pragma unroll
      for (int it = 0; it < 2; ++it) {
        int seg = it * 256 + tid;
        int row = seg >> 2, cs = seg & 3;
        GLD16(Vg + (long)row * SSD + jb + c * 32 + cs * 8,
              &Vsm[c * 4096 + (it * 256 + wv * 64) * 8]);
      }
    __syncthreads();  // drains vmcnt

    // ---- S = Q K^T for this wave's 32 rows x all 128 cols ----
    floatx4 sacc[2][8];
#pragma unroll
    for (int i = 0; i < 2; ++i)
#pragma unroll
      for (int n = 0; n < 8; ++n)
        sacc[i][n] = (floatx4){0.f, 0.f, 0.f, 0.f};
#pragma unroll
    for (int c = 0; c < 6; ++c) {
      short8 fb[8];
#pragma unroll
      for (int n = 0; n < 8; ++n)
        fb[n] = *(const short8*)&Ksm[c * 4096 + (n * 16 + fr) * 32 + q8];
#pragma unroll
      for (int n = 0; n < 8; ++n) {
        sacc[0][n] = __builtin_amdgcn_mfma_f32_16x16x32_bf16(qf[0][c], fb[n], sacc[0][n], 0, 0, 0);
        sacc[1][n] = __builtin_amdgcn_mfma_f32_16x16x32_bf16(qf[1][c], fb[n], sacc[1][n], 0, 0, 0);
      }
    }

    // ---- online softmax (rows live entirely in this wave; 16-lane reductions) ----
    const bool diag = (j == qt);
#pragma unroll
    for (int i = 0; i < 2; ++i)
#pragma unroll
      for (int r = 0; r < 4; ++r) {
        int rowg = q0 + wrow + i * 16 + g4 * 4 + r;
        float mx = -1e30f;
#pragma unroll
        for (int n = 0; n < 8; ++n) {
          float v = sacc[i][n][r] * SCALEF;
          if (diag && (jb + n * 16 + fr) > rowg) v = -1e30f;
          sacc[i][n][r] = v;
          mx = fmaxf(mx, v);
        }
#pragma unroll
        for (int off = 1; off < 16; off <<= 1) mx = fmaxf(mx, __shfl_xor(mx, off, 64));
        float mnew = fmaxf(mi[i][r], mx);
        float alpha = __expf(mi[i][r] - mnew);
        mi[i][r] = mnew;
        float rs = 0.f;
#pragma unroll
        for (int n = 0; n < 8; ++n) {
          float p = __expf(sacc[i][n][r] - mnew);
          sacc[i][n][r] = p;
          rs += p;
        }
#pragma unroll
        for (int off = 1; off < 16; off <<= 1) rs += __shfl_xor(rs, off, 64);
        li[i][r] = li[i][r] * alpha + rs;
#pragma unroll
        for (int n = 0; n < 8; ++n) {
          oacc[i][n][0 ? 0 : 0] = oacc[i][n][0 ? 0 : 0];  // no-op keep structure
        }
#pragma unroll
        for (int n = 0; n < 8; ++n) oacc[i][n][r] *= alpha;
      }

    // ---- P -> LDS (C/D layout -> A-operand layout), aliasing dead K region ----
    __syncthreads();  // all waves done reading Ksm fragments
#pragma unroll
    for (int i = 0; i < 2; ++i)
#pragma unroll
      for (int n = 0; n < 8; ++n) {
        int c2 = n >> 1;
        int col = (n & 1) * 16 + fr;
#pragma unroll
        for (int r = 0; r < 4; ++r) {
          int m = wrow + i * 16 + g4 * 4 + r;
          Psm[c2 * 4096 + m * 32 + col] = __float2bfloat16(sacc[i][n][r]);
        }
      }
    // same-wave write->read ordering via lgkmcnt (compiler-inserted)

    // ---- O += P V ----
#pragma unroll
    for (int c2 = 0; c2 < 4; ++c2) {
      short8 pf0 = *(const short8*)&Psm[c2 * 4096 + (wrow + fr) * 32 + q8];
      short8 pf1 = *(const short8*)&Psm[c2 * 4096 + (wrow + 16 + fr) * 32 + q8];
#pragma unroll
      for (int dn = 0; dn < 8; ++dn) {
        short8 vf = *(const short8*)&Vsm[c2 * 4096 + (dn * 16 + fr) * 32 + q8];
        oacc[0][dn] = __builtin_amdgcn_mfma_f32_16x16x32_bf16(pf0, vf, oacc[0][dn], 0, 0, 0);
        oacc[1][dn] = __builtin_amdgcn_mfma_f32_16x16x32_bf16(pf1, vf, oacc[1][dn], 0, 0, 0);
      }
    }
  }

  // ---- normalize and write O directly in (B,S,NH*128) layout ----
#pragma unroll
  for (int i = 0; i < 2; ++i)
#pragma unroll
    for (int r = 0; r < 4; ++r) {
      float inv = 1.f / li[i][r];
      int m = q0 + wrow + i * 16 + g4 * 4 + r;
      bf16* orow = attnall + ((long)(b * SSD + m) * NHD + h) * 128;
#pragma unroll
      for (int dn = 0; dn < 8; ++dn)
        orow[dn * 16 + fr] = __float2bfloat16(oacc[i][dn][r] * inv);
    }
}

// ---------------- fp32 -> bf16 convert (optional zero row-padding) ----------------
__global__ void cvt_pad(const float* __restrict__ src, bf16* __restrict__ dst,
                        int srcRows, int dstRows, int cols)
{
  long n = (long)dstRows * cols;
  long i = (long)blockIdx.x * 256 + threadIdx.x;
  if (i >= n) return;
  if (srcRows == dstRows) { dst[i] = __float2bfloat16(src[i]); return; }
  long r = i / cols, c = i - r * cols;
  dst[i] = __float2bfloat16(r < (long)srcRows ? src[r * cols + c] : 0.f);
}

// ---------------- rmsnorm (row per block), bf16 in (+opt fp32 bias), bf16 out ----------------
template<int L>
__global__ __launch_bounds__(256)
void rmsnorm_k(const bf16* __restrict__ in, const float* __restrict__ bias,
               const float* __restrict__ w, bf16* __restrict__ out, int ldin)
{
  constexpr int NIT = L / 256;
  long r = blockIdx.x;
  const bf16* row = in + r * ldin;
  int tid = threadIdx.x;
  float v[NIT];
  float ss = 0.f;
#pragma unroll
  for (int i = 0; i < NIT; ++i) {
    int c = tid + (i << 8);
    float x = __bfloat162float(row[c]) + (bias ? bias[c] : 0.f);
    v[i] = x;
    ss += x * x;
  }
  ss = block_sum(ss);
  float sc = rsqrtf(ss / (float)L + EPSF);
#pragma unroll
  for (int i = 0; i < NIT; ++i) {
    int c = tid + (i << 8);
    out[r * L + c] = __float2bfloat16(v[i] * sc * w[c]);
  }
}

// ---------------- build Q (rope on last 64) -> (B,NH,S,192) bf16 ----------------
__global__ void build_q(const bf16* __restrict__ Qf, const float* __restrict__ freqs,
                        bf16* __restrict__ Qh)
{
  int idx = blockIdx.x * 256 + threadIdx.x;
  if (idx >= BSD * NHD * 96) return;
  int j = idx % 96;
  int h = (idx / 96) % NHD;
  int srow = idx / (96 * NHD);
  int s = srow & (SSD - 1);
  int b = srow >> 11;
  const bf16* src = Qf + (long)srow * (NHD * QKD) + h * QKD + 2 * j;
  float x0 = __bfloat162float(src[0]), x1 = __bfloat162float(src[1]), y0, y1;
  if (j >= 64) {
    int i = j - 64;
    float f = freqs[s * 32 + i];
    float c = cosf(f), sn = sinf(f);
    y0 = x0 * c - x1 * sn;
    y1 = x0 * sn + x1 * c;
  } else { y0 = x0; y1 = x1; }
  bf16* dst = Qh + ((long)(b * NHD + h) * SSD + s) * QKD + 2 * j;
  dst[0] = __float2bfloat16(y0);
  dst[1] = __float2bfloat16(y1);
}

// ---------------- build K = [K_nope | rope(K_rope) bcast] -> (B,NH,S,192) bf16 ----------------
__global__ void build_k(const bf16* __restrict__ kvf, const bf16* __restrict__ kvkr,
                        const float* __restrict__ kvb, const float* __restrict__ freqs,
                        bf16* __restrict__ Kh)
{
  int idx = blockIdx.x * 256 + threadIdx.x;
  if (idx >= BSD * NHD * 96) return;
  int j = idx % 96;
  int h = (idx / 96) % NHD;
  int srow = idx / (96 * NHD);
  int s = srow & (SSD - 1);
  int b = srow >> 11;
  float y0, y1;
  if (j < 64) {
    const bf16* src = kvf + (long)srow * 4096 + h * 256 + 2 * j;
    y0 = __bfloat162float(src[0]); y1 = __bfloat162float(src[1]);
  } else {
    int i = j - 64;
    float x0 = __bfloat162float(kvkr[(long)srow * KVPAD + 512 + 2 * i]) + kvb[512 + 2 * i];
    float x1 = __bfloat162float(kvkr[(long)srow * KVPAD + 513 + 2 * i]) + kvb[513 + 2 * i];
    float f = freqs[s * 32 + i];
    float c = cosf(f), sn = sinf(f);
    y0 = x0 * c - x1 * sn;
    y1 = x0 * sn + x1 * c;
  }
  bf16* dst = Kh + ((long)(b * NHD + h) * SSD + s) * QKD + 2 * j;
  dst[0] = __float2bfloat16(y0);
  dst[1] = __float2bfloat16(y1);
}

// ---------------- build V^T: kv(B,S,NH,256)[...,128:256] -> Vt (BH,128,S) bf16 ----------------
__global__ __launch_bounds__(256)
void build_vt(const bf16* __restrict__ kvf, bf16* __restrict__ Vt)
{
  __shared__ float t[32][33];
  int s0 = blockIdx.x * 32, d0 = blockIdx.y * 32, z = blockIdx.z;
  int b = z / NHD, h = z % NHD;
  int tx = threadIdx.x, ty = threadIdx.y;  // 32 x 8
#pragma unroll
  for (int r = 0; r < 4; ++r) {
    int sl = ty + r * 8;
    t[sl][tx] = __bfloat162float(kvf[(long)(b * SSD + s0 + sl) * 4096 + h * 256 + 128 + d0 + tx]);
  }
  __syncthreads();
#pragma unroll
  for (int r = 0; r < 4; ++r) {
    int dl = ty + r * 8;
    Vt[((long)z * 128 + d0 + dl) * SSD + s0 + tx] = __float2bfloat16(t[tx][dl]);
  }
}

// ---------------- diagnostic: ws too small ----------------
__global__ void diag_fill(float* out) { out[blockIdx.x * 256 + threadIdx.x] = 1000.0f; }

extern "C" void kernel_launch(void* const* d_in, const int* in_sizes, int n_in,
                              void* d_out, int out_size, void* d_ws, size_t ws_size,
                              hipStream_t stream)
{
  const float* x     = (const float*)d_in[0];
  const float* freqs = (const float*)d_in[1];
  const float* Wqd   = (const float*)d_in[3];
  const float* Wqdb  = (const float*)d_in[4];
  const float* qnw   = (const float*)d_in[5];
  const float* Wqu   = (const float*)d_in[6];
  const float* Wqub  = (const float*)d_in[7];
  const float* Wkvd  = (const float*)d_in[8];
  const float* Wkvdb = (const float*)d_in[9];
  const float* kvnw  = (const float*)d_in[10];
  const float* Wkvu  = (const float*)d_in[11];
  const float* Wkvub = (const float*)d_in[12];
  const float* Wo    = (const float*)d_in[13];
  const float* Wob   = (const float*)d_in[14];
  float* out = (float*)d_out;

  char* ws = (char*)d_ws;
  size_t off = 0;
  auto alloc = [&](size_t bytes) {
    void* p = ws + off;
    off += (bytes + 255) & ~(size_t)255;
    return p;
  };

  bf16* Wqd16  = (bf16*)alloc((size_t)QLORA * DIMD * 2);
  bf16* Wqu16  = (bf16*)alloc((size_t)3072 * QLORA * 2);
  bf16* Wkvd16 = (bf16*)alloc((size_t)KVPAD * DIMD * 2);
  bf16* Wkvu16 = (bf16*)alloc((size_t)4096 * KVLORA * 2);
  bf16* Wo16   = (bf16*)alloc((size_t)DIMD * 2048 * 2);
  bf16* x16    = (bf16*)alloc((size_t)BSD * DIMD * 2);
  bf16* Ra     = (bf16*)alloc((size_t)BSD * QLORA * 2);   // qdown, then kvkr
  bf16* Rb     = (bf16*)alloc((size_t)BSD * QLORA * 2);   // qlat, then kvlat
  bf16* Rc     = (bf16*)alloc((size_t)BSD * 4096 * 2);    // Qf, then kvf, then attnall
  bf16* Qh16   = (bf16*)alloc((size_t)BHN * SSD * QKD * 2);
  bf16* Kh16   = (bf16*)alloc((size_t)BHN * SSD * QKD * 2);
  bf16* Vt16   = (bf16*)alloc((size_t)BHN * 128 * SSD * 2);

  bf16* qdown   = Ra;  bf16* kvkr    = Ra;
  bf16* qlat16  = Rb;  bf16* kvlat16 = Rb;
  bf16* Qf      = Rc;  bf16* kvf     = Rc;  bf16* attnall = Rc;

  if (off > ws_size) { diag_fill<<<8, 256, 0, stream>>>(out); return; }

  dim3 blk(256);
  auto cdiv = [](long a, long b) { return (int)((a + b - 1) / b); };

  // --- converts to bf16 ---
  cvt_pad<<<cdiv((long)BSD * DIMD, 256), blk, 0, stream>>>(x, x16, 1, 1, BSD * DIMD);
  cvt_pad<<<cdiv((long)QLORA * DIMD, 256), blk, 0, stream>>>(Wqd, Wqd16, 1, 1, QLORA * DIMD);
  cvt_pad<<<cdiv((long)3072 * QLORA, 256), blk, 0, stream>>>(Wqu, Wqu16, 1, 1, 3072 * QLORA);
  cvt_pad<<<cdiv((long)KVPAD * DIMD, 256), blk, 0, stream>>>(Wkvd, Wkvd16, 576, KVPAD, DIMD);
  cvt_pad<<<cdiv((long)4096 * KVLORA, 256), blk, 0, stream>>>(Wkvu, Wkvu16, 1, 1, 4096 * KVLORA);
  cvt_pad<<<cdiv((long)DIMD * 2048, 256), blk, 0, stream>>>(Wo, Wo16, 1, 1, DIMD * 2048);

  // --- Q path ---
  gemm_bt<true><<<dim3(QLORA / 128, BSD / 128, 1), blk, 0, stream>>>(
      x16, Wqd16, Wqdb, qdown, BSD, QLORA, DIMD, 0, 0, 0, QLORA);
  rmsnorm_k<QLORA><<<BSD, blk, 0, stream>>>(qdown, nullptr, qnw, qlat16, QLORA);
  gemm_bt<true><<<dim3(3072 / 128, BSD / 128, 1), blk, 0, stream>>>(
      qlat16, Wqu16, Wqub, Qf, BSD, 3072, QLORA, 0, 0, 0, 3072);
  build_q<<<cdiv((long)BSD * NHD * 96, 256), blk, 0, stream>>>(Qf, freqs, Qh16);

  // --- KV path ---
  gemm_bt<true><<<dim3(KVPAD / 128, BSD / 128, 1), blk, 0, stream>>>(
      x16, Wkvd16, nullptr, kvkr, BSD, KVPAD, DIMD, 0, 0, 0, KVPAD);
  rmsnorm_k<KVLORA><<<BSD, blk, 0, stream>>>(kvkr, Wkvdb, kvnw, kvlat16, KVPAD);
  gemm_bt<true><<<dim3(4096 / 128, BSD / 128, 1), blk, 0, stream>>>(
      kvlat16, Wkvu16, Wkvub, kvf, BSD, 4096, KVLORA, 0, 0, 0, 4096);
  build_k<<<cdiv((long)BSD * NHD * 96, 256), blk, 0, stream>>>(kvf, kvkr, Wkvdb, freqs, Kh16);
  build_vt<<<dim3(SSD / 32, 128 / 32, BHN), dim3(32, 8), 0, stream>>>(kvf, Vt16);

  // --- fused flash attention: writes O directly in (B,S,NH*128) ---
  flash_attn<<<dim3(SSD / 128, BHN), blk, 0, stream>>>(Qh16, Kh16, Vt16, attnall);

  // --- output projection (fp32 out) ---
  gemm_bt<false><<<dim3(2048 / 128, BSD / 128, 1), blk, 0, stream>>>(
      attnall, Wo16, Wob, out, BSD, DIMD, 2048, 0, 0, 0, DIMD);
}

// Round 4
// 571.115 us; speedup vs baseline: 1.6523x; 1.1340x over previous
//
#include <hip/hip_runtime.h>
#include <hip/hip_bf16.h>

#define DIMD 2048
#define NHD 16
#define QLORA 1536
#define KVLORA 512
#define QKD 192
#define BBD 2
#define SSD 2048
#define BSD (BBD*SSD)       // 4096 tokens
#define KVPAD 640           // 576 padded to multiple of 128
#define BHN (BBD*NHD)       // 32 (b,h) pairs
#define EPSF 1.1920929e-07f
#define SCALEF 0.07216878364870322f  // 192^-0.5

typedef __hip_bfloat16 bf16;
typedef __attribute__((ext_vector_type(8))) short short8;
typedef __attribute__((ext_vector_type(4))) float floatx4;

typedef __attribute__((address_space(1))) char as1_char;
typedef __attribute__((address_space(3))) char as3_char;
#define GLD16(g, l) __builtin_amdgcn_global_load_lds((as1_char*)(g), (as3_char*)(l), 16, 0, 0)

// ---------------- block reduction (256 threads = 4 waves) ----------------
__device__ __forceinline__ float block_sum(float x) {
#pragma unroll
  for (int o = 32; o > 0; o >>= 1) x += __shfl_xor(x, o, 64);
  __shared__ float red[4];
  __syncthreads();
  if ((threadIdx.x & 63) == 0) red[threadIdx.x >> 6] = x;
  __syncthreads();
  return red[0] + red[1] + red[2] + red[3];
}

// ---------------- generic bf16 MFMA GEMM:  C = A(MxK) * B(NxK)^T + bias ----------------
template<bool STORE_BF16>
__global__ __launch_bounds__(256)
void gemm_bt(const bf16* __restrict__ A, const bf16* __restrict__ Bm,
             const float* __restrict__ bias, void* __restrict__ Cp,
             int M, int N, int K, long sA, long sB, long sC, int ldc)
{
  int m0 = blockIdx.y * 128, n0 = blockIdx.x * 128;
  long z = blockIdx.z;
  A  += z * sA;
  Bm += z * sB;

  __shared__ __align__(16) bf16 Asm[128 * 32];
  __shared__ __align__(16) bf16 Bsm[128 * 32];

  const int tid  = threadIdx.x;
  const int lane = tid & 63;
  const int wv   = tid >> 6;
  const int wm   = (wv >> 1) << 6;
  const int wn   = (wv & 1) << 6;
  const int fr   = lane & 15;
  const int q8   = (lane >> 4) << 3;

  floatx4 acc[4][4];
#pragma unroll
  for (int i = 0; i < 4; ++i)
#pragma unroll
    for (int j = 0; j < 4; ++j)
      acc[i][j] = (floatx4){0.f, 0.f, 0.f, 0.f};

  for (int k0 = 0; k0 < K; k0 += 32) {
    __syncthreads();
#pragma unroll
    for (int it = 0; it < 2; ++it) {
      int seg = it * 256 + tid;
      int row = seg >> 2, cs = seg & 3;
      GLD16(A  + (long)(m0 + row) * K + k0 + cs * 8, &Asm[(it * 256 + wv * 64) * 8]);
      GLD16(Bm + (long)(n0 + row) * K + k0 + cs * 8, &Bsm[(it * 256 + wv * 64) * 8]);
    }
    __syncthreads();

    short8 fa[4], fb[4];
#pragma unroll
    for (int t = 0; t < 4; ++t) fa[t] = *(const short8*)&Asm[(wm + t * 16 + fr) * 32 + q8];
#pragma unroll
    for (int t = 0; t < 4; ++t) fb[t] = *(const short8*)&Bsm[(wn + t * 16 + fr) * 32 + q8];
#pragma unroll
    for (int i = 0; i < 4; ++i)
#pragma unroll
      for (int j = 0; j < 4; ++j)
        acc[i][j] = __builtin_amdgcn_mfma_f32_16x16x32_bf16(fa[i], fb[j], acc[i][j], 0, 0, 0);
  }

  long cb = z * sC;
  int rq = (lane >> 4) * 4;
#pragma unroll
  for (int i = 0; i < 4; ++i) {
#pragma unroll
    for (int j = 0; j < 4; ++j) {
      int col = n0 + wn + j * 16 + fr;
      float bv = bias ? bias[col] : 0.f;
#pragma unroll
      for (int r = 0; r < 4; ++r) {
        int rowg = m0 + wm + i * 16 + rq + r;
        float v = acc[i][j][r] + bv;
        if (STORE_BF16)
          ((bf16*)Cp)[cb + (long)rowg * ldc + col] = __float2bfloat16(v);
        else
          ((float*)Cp)[cb + (long)rowg * ldc + col] = v;
      }
    }
  }
}

// ---------------- fused flash attention (causal), balanced tile pairs ----------------
// 512 threads = 8 waves, each wave owns 16 q-rows. Block p processes row-tiles
// {15-p, p}: exactly 17 j-iterations for every block (deterministic balance).
__global__ __launch_bounds__(512, 2)
void flash_attn(const bf16* __restrict__ Qh, const bf16* __restrict__ Kh,
                const bf16* __restrict__ Vt, bf16* __restrict__ attnall)
{
  const int p = blockIdx.x;        // 0..7
  const int z = blockIdx.y;        // b*NH + h
  const int b = z >> 4, h = z & 15;

  const bf16* Qg = Qh + (long)z * SSD * QKD;
  const bf16* Kg = Kh + (long)z * SSD * QKD;
  const bf16* Vg = Vt + (long)z * 128 * SSD;

  __shared__ __align__(16) bf16 Ksm[6 * 4096];  // 48KB; P aliases first 32KB; Q staged here too
  __shared__ __align__(16) bf16 Vsm[4 * 4096];  // 32KB
  bf16* Psm = Ksm;

  const int tid  = threadIdx.x;
  const int lane = tid & 63;
  const int wv   = tid >> 6;       // 0..7
  const int fr   = lane & 15;
  const int g4   = lane >> 4;
  const int q8   = g4 << 3;
  const int srow = tid >> 2;       // staging row 0..127
  const int scs  = tid & 3;        // staging 16B segment within row-chunk

#pragma unroll 1
  for (int t = 0; t < 2; ++t) {
    const int qt = t ? p : 15 - p;
    const int q0 = qt * 128;

    __syncthreads();  // prior tile's P/V LDS reads complete
    // --- stage Q tile through Ksm, pull fragments to regs ---
#pragma unroll
    for (int c = 0; c < 6; ++c)
      GLD16(Qg + (long)(q0 + srow) * QKD + c * 32 + scs * 8, &Ksm[c * 4096 + wv * 512]);
    __syncthreads();
    short8 qf[6];
#pragma unroll
    for (int c = 0; c < 6; ++c)
      qf[c] = *(const short8*)&Ksm[c * 4096 + (wv * 16 + fr) * 32 + q8];

    floatx4 oacc[8];
#pragma unroll
    for (int n = 0; n < 8; ++n) oacc[n] = (floatx4){0.f, 0.f, 0.f, 0.f};
    float mi[4], li[4];
#pragma unroll
    for (int r = 0; r < 4; ++r) { mi[r] = -1e30f; li[r] = 0.f; }

    for (int j = 0; j <= qt; ++j) {
      const int jb = j * 128;
      __syncthreads();  // qf reads / prev-iter P & V reads complete
#pragma unroll
      for (int c = 0; c < 6; ++c)
        GLD16(Kg + (long)(jb + srow) * QKD + c * 32 + scs * 8, &Ksm[c * 4096 + wv * 512]);
#pragma unroll
      for (int c = 0; c < 4; ++c)
        GLD16(Vg + (long)srow * SSD + jb + c * 32 + scs * 8, &Vsm[c * 4096 + wv * 512]);
      __syncthreads();  // drains vmcnt

      // ---- S = Q K^T : this wave's 16 rows x 128 cols ----
      floatx4 sacc[8];
#pragma unroll
      for (int n = 0; n < 8; ++n) sacc[n] = (floatx4){0.f, 0.f, 0.f, 0.f};
#pragma unroll
      for (int c = 0; c < 6; ++c) {
#pragma unroll
        for (int n = 0; n < 8; ++n) {
          short8 fb = *(const short8*)&Ksm[c * 4096 + (n * 16 + fr) * 32 + q8];
          sacc[n] = __builtin_amdgcn_mfma_f32_16x16x32_bf16(qf[c], fb, sacc[n], 0, 0, 0);
        }
      }

      // ---- online softmax (rows fully inside this wave; 16-lane reductions) ----
      const bool diag = (j == qt);
#pragma unroll
      for (int r = 0; r < 4; ++r) {
        int rowg = q0 + wv * 16 + g4 * 4 + r;
        float mx = -1e30f;
#pragma unroll
        for (int n = 0; n < 8; ++n) {
          float v = sacc[n][r] * SCALEF;
          if (diag && (jb + n * 16 + fr) > rowg) v = -1e30f;
          sacc[n][r] = v;
          mx = fmaxf(mx, v);
        }
#pragma unroll
        for (int off = 1; off < 16; off <<= 1) mx = fmaxf(mx, __shfl_xor(mx, off, 64));
        float mnew = fmaxf(mi[r], mx);
        float alpha = __expf(mi[r] - mnew);
        mi[r] = mnew;
        float rs = 0.f;
#pragma unroll
        for (int n = 0; n < 8; ++n) {
          float pv = __expf(sacc[n][r] - mnew);
          sacc[n][r] = pv;
          rs += pv;
        }
#pragma unroll
        for (int off = 1; off < 16; off <<= 1) rs += __shfl_xor(rs, off, 64);
        li[r] = li[r] * alpha + rs;
#pragma unroll
        for (int n = 0; n < 8; ++n) oacc[n][r] *= alpha;
      }

      // ---- P -> LDS (C/D layout -> A-operand layout), aliasing dead K region ----
      __syncthreads();  // all waves done reading Ksm fragments
#pragma unroll
      for (int n = 0; n < 8; ++n) {
        int c2 = n >> 1;
        int col = (n & 1) * 16 + fr;
#pragma unroll
        for (int r = 0; r < 4; ++r) {
          int m = wv * 16 + g4 * 4 + r;
          Psm[c2 * 4096 + m * 32 + col] = __float2bfloat16(sacc[n][r]);
        }
      }
      // same-wave write->read ordering via compiler-inserted lgkmcnt

      // ---- O += P V ----
#pragma unroll
      for (int c2 = 0; c2 < 4; ++c2) {
        short8 pf = *(const short8*)&Psm[c2 * 4096 + (wv * 16 + fr) * 32 + q8];
#pragma unroll
        for (int dn = 0; dn < 8; ++dn) {
          short8 vf = *(const short8*)&Vsm[c2 * 4096 + (dn * 16 + fr) * 32 + q8];
          oacc[dn] = __builtin_amdgcn_mfma_f32_16x16x32_bf16(pf, vf, oacc[dn], 0, 0, 0);
        }
      }
    }

    // ---- normalize and write O directly in (B,S,NH*128) layout ----
#pragma unroll
    for (int r = 0; r < 4; ++r) {
      float inv = 1.f / li[r];
      int m = q0 + wv * 16 + g4 * 4 + r;
      bf16* orow = attnall + ((long)(b * SSD + m) * NHD + h) * 128;
#pragma unroll
      for (int dn = 0; dn < 8; ++dn)
        orow[dn * 16 + fr] = __float2bfloat16(oacc[dn][r] * inv);
    }
  }
}

// ---------------- fused fp32 -> bf16 converts (float4-vectorized) ----------------
__device__ __forceinline__ void cvt4(const float* __restrict__ s, bf16* __restrict__ d,
                                     long se, long de) {
  float4 v = *(const float4*)(s + se);
  union { bf16 h[4]; uint2 u; } o;
  o.h[0] = __float2bfloat16(v.x); o.h[1] = __float2bfloat16(v.y);
  o.h[2] = __float2bfloat16(v.z); o.h[3] = __float2bfloat16(v.w);
  *(uint2*)(d + de) = o.u;
}

#define NX4   ((long)BSD * DIMD / 4)
#define NQD4  ((long)QLORA * DIMD / 4)
#define NQU4  ((long)3072 * QLORA / 4)
#define NKVD4 ((long)KVPAD * DIMD / 4)
#define NKVU4 ((long)4096 * KVLORA / 4)
#define NWO4  ((long)DIMD * 2048 / 4)

__global__ __launch_bounds__(256)
void cvt_all(const float* __restrict__ x, const float* __restrict__ wqd,
             const float* __restrict__ wqu, const float* __restrict__ wkvd,
             const float* __restrict__ wkvu, const float* __restrict__ wo,
             bf16* __restrict__ dx, bf16* __restrict__ dwqd, bf16* __restrict__ dwqu,
             bf16* __restrict__ dwkvd, bf16* __restrict__ dwkvu, bf16* __restrict__ dwo)
{
  long i = (long)blockIdx.x * 256 + threadIdx.x;
  if (i < NX4) { cvt4(x, dx, i * 4, i * 4); return; }
  i -= NX4;
  if (i < NQD4) { cvt4(wqd, dwqd, i * 4, i * 4); return; }
  i -= NQD4;
  if (i < NQU4) { cvt4(wqu, dwqu, i * 4, i * 4); return; }
  i -= NQU4;
  if (i < NKVD4) {
    long e = i * 4;
    long r = e >> 11;             // dst row (cols = 2048)
    if (r < 576) cvt4(wkvd, dwkvd, e, e);   // src same linear index while r < 576
    else *(uint2*)(dwkvd + e) = (uint2){0u, 0u};
    return;
  }
  i -= NKVD4;
  if (i < NKVU4) { cvt4(wkvu, dwkvu, i * 4, i * 4); return; }
  i -= NKVU4;
  if (i < NWO4) { cvt4(wo, dwo, i * 4, i * 4); return; }
}

// ---------------- rmsnorm (row per block), bf16 in (+opt fp32 bias), bf16 out ----------------
template<int L>
__global__ __launch_bounds__(256)
void rmsnorm_k(const bf16* __restrict__ in, const float* __restrict__ bias,
               const float* __restrict__ w, bf16* __restrict__ out, int ldin)
{
  constexpr int NIT = L / 256;
  long r = blockIdx.x;
  const bf16* row = in + r * ldin;
  int tid = threadIdx.x;
  float v[NIT];
  float ss = 0.f;
#pragma unroll
  for (int i = 0; i < NIT; ++i) {
    int c = tid + (i << 8);
    float x = __bfloat162float(row[c]) + (bias ? bias[c] : 0.f);
    v[i] = x;
    ss += x * x;
  }
  ss = block_sum(ss);
  float sc = rsqrtf(ss / (float)L + EPSF);
#pragma unroll
  for (int i = 0; i < NIT; ++i) {
    int c = tid + (i << 8);
    out[r * L + c] = __float2bfloat16(v[i] * sc * w[c]);
  }
}

// ---------------- build Q (rope on last 64) -> (B,NH,S,192) bf16 ----------------
__global__ void build_q(const bf16* __restrict__ Qf, const float* __restrict__ freqs,
                        bf16* __restrict__ Qh)
{
  int idx = blockIdx.x * 256 + threadIdx.x;
  if (idx >= BSD * NHD * 96) return;
  int j = idx % 96;
  int h = (idx / 96) % NHD;
  int srow = idx / (96 * NHD);
  int s = srow & (SSD - 1);
  int b = srow >> 11;
  const bf16* src = Qf + (long)srow * (NHD * QKD) + h * QKD + 2 * j;
  float x0 = __bfloat162float(src[0]), x1 = __bfloat162float(src[1]), y0, y1;
  if (j >= 64) {
    int i = j - 64;
    float f = freqs[s * 32 + i];
    float c = cosf(f), sn = sinf(f);
    y0 = x0 * c - x1 * sn;
    y1 = x0 * sn + x1 * c;
  } else { y0 = x0; y1 = x1; }
  bf16* dst = Qh + ((long)(b * NHD + h) * SSD + s) * QKD + 2 * j;
  dst[0] = __float2bfloat16(y0);
  dst[1] = __float2bfloat16(y1);
}

// ---------------- build K = [K_nope | rope(K_rope) bcast] -> (B,NH,S,192) bf16 ----------------
__global__ void build_k(const bf16* __restrict__ kvf, const bf16* __restrict__ kvkr,
                        const float* __restrict__ kvb, const float* __restrict__ freqs,
                        bf16* __restrict__ Kh)
{
  int idx = blockIdx.x * 256 + threadIdx.x;
  if (idx >= BSD * NHD * 96) return;
  int j = idx % 96;
  int h = (idx / 96) % NHD;
  int srow = idx / (96 * NHD);
  int s = srow & (SSD - 1);
  int b = srow >> 11;
  float y0, y1;
  if (j < 64) {
    const bf16* src = kvf + (long)srow * 4096 + h * 256 + 2 * j;
    y0 = __bfloat162float(src[0]); y1 = __bfloat162float(src[1]);
  } else {
    int i = j - 64;
    float x0 = __bfloat162float(kvkr[(long)srow * KVPAD + 512 + 2 * i]) + kvb[512 + 2 * i];
    float x1 = __bfloat162float(kvkr[(long)srow * KVPAD + 513 + 2 * i]) + kvb[513 + 2 * i];
    float f = freqs[s * 32 + i];
    float c = cosf(f), sn = sinf(f);
    y0 = x0 * c - x1 * sn;
    y1 = x0 * sn + x1 * c;
  }
  bf16* dst = Kh + ((long)(b * NHD + h) * SSD + s) * QKD + 2 * j;
  dst[0] = __float2bfloat16(y0);
  dst[1] = __float2bfloat16(y1);
}

// ---------------- build V^T: kv(B,S,NH,256)[...,128:256] -> Vt (BH,128,S) bf16 ----------------
__global__ __launch_bounds__(256)
void build_vt(const bf16* __restrict__ kvf, bf16* __restrict__ Vt)
{
  __shared__ float t[32][33];
  int s0 = blockIdx.x * 32, d0 = blockIdx.y * 32, z = blockIdx.z;
  int b = z / NHD, h = z % NHD;
  int tx = threadIdx.x, ty = threadIdx.y;  // 32 x 8
#pragma unroll
  for (int r = 0; r < 4; ++r) {
    int sl = ty + r * 8;
    t[sl][tx] = __bfloat162float(kvf[(long)(b * SSD + s0 + sl) * 4096 + h * 256 + 128 + d0 + tx]);
  }
  __syncthreads();
#pragma unroll
  for (int r = 0; r < 4; ++r) {
    int dl = ty + r * 8;
    Vt[((long)z * 128 + d0 + dl) * SSD + s0 + tx] = __float2bfloat16(t[tx][dl]);
  }
}

// ---------------- diagnostic: ws too small ----------------
__global__ void diag_fill(float* out) { out[blockIdx.x * 256 + threadIdx.x] = 1000.0f; }

extern "C" void kernel_launch(void* const* d_in, const int* in_sizes, int n_in,
                              void* d_out, int out_size, void* d_ws, size_t ws_size,
                              hipStream_t stream)
{
  const float* x     = (const float*)d_in[0];
  const float* freqs = (const float*)d_in[1];
  const float* Wqd   = (const float*)d_in[3];
  const float* Wqdb  = (const float*)d_in[4];
  const float* qnw   = (const float*)d_in[5];
  const float* Wqu   = (const float*)d_in[6];
  const float* Wqub  = (const float*)d_in[7];
  const float* Wkvd  = (const float*)d_in[8];
  const float* Wkvdb = (const float*)d_in[9];
  const float* kvnw  = (const float*)d_in[10];
  const float* Wkvu  = (const float*)d_in[11];
  const float* Wkvub = (const float*)d_in[12];
  const float* Wo    = (const float*)d_in[13];
  const float* Wob   = (const float*)d_in[14];
  float* out = (float*)d_out;

  char* ws = (char*)d_ws;
  size_t off = 0;
  auto alloc = [&](size_t bytes) {
    void* p = ws + off;
    off += (bytes + 255) & ~(size_t)255;
    return p;
  };

  bf16* Wqd16  = (bf16*)alloc((size_t)QLORA * DIMD * 2);
  bf16* Wqu16  = (bf16*)alloc((size_t)3072 * QLORA * 2);
  bf16* Wkvd16 = (bf16*)alloc((size_t)KVPAD * DIMD * 2);
  bf16* Wkvu16 = (bf16*)alloc((size_t)4096 * KVLORA * 2);
  bf16* Wo16   = (bf16*)alloc((size_t)DIMD * 2048 * 2);
  bf16* x16    = (bf16*)alloc((size_t)BSD * DIMD * 2);
  bf16* Ra     = (bf16*)alloc((size_t)BSD * QLORA * 2);   // qdown, then kvkr
  bf16* Rb     = (bf16*)alloc((size_t)BSD * QLORA * 2);   // qlat, then kvlat
  bf16* Rc     = (bf16*)alloc((size_t)BSD * 4096 * 2);    // Qf, then kvf, then attnall
  bf16* Qh16   = (bf16*)alloc((size_t)BHN * SSD * QKD * 2);
  bf16* Kh16   = (bf16*)alloc((size_t)BHN * SSD * QKD * 2);
  bf16* Vt16   = (bf16*)alloc((size_t)BHN * 128 * SSD * 2);

  bf16* qdown   = Ra;  bf16* kvkr    = Ra;
  bf16* qlat16  = Rb;  bf16* kvlat16 = Rb;
  bf16* Qf      = Rc;  bf16* kvf     = Rc;  bf16* attnall = Rc;

  if (off > ws_size) { diag_fill<<<8, 256, 0, stream>>>(out); return; }

  dim3 blk(256);
  auto cdiv = [](long a, long b) { return (int)((a + b - 1) / b); };

  // --- all fp32->bf16 converts in one dispatch ---
  long tot4 = NX4 + NQD4 + NQU4 + NKVD4 + NKVU4 + NWO4;
  cvt_all<<<cdiv(tot4, 256), blk, 0, stream>>>(x, Wqd, Wqu, Wkvd, Wkvu, Wo,
                                               x16, Wqd16, Wqu16, Wkvd16, Wkvu16, Wo16);

  // --- Q path ---
  gemm_bt<true><<<dim3(QLORA / 128, BSD / 128, 1), blk, 0, stream>>>(
      x16, Wqd16, Wqdb, qdown, BSD, QLORA, DIMD, 0, 0, 0, QLORA);
  rmsnorm_k<QLORA><<<BSD, blk, 0, stream>>>(qdown, nullptr, qnw, qlat16, QLORA);
  gemm_bt<true><<<dim3(3072 / 128, BSD / 128, 1), blk, 0, stream>>>(
      qlat16, Wqu16, Wqub, Qf, BSD, 3072, QLORA, 0, 0, 0, 3072);
  build_q<<<cdiv((long)BSD * NHD * 96, 256), blk, 0, stream>>>(Qf, freqs, Qh16);

  // --- KV path ---
  gemm_bt<true><<<dim3(KVPAD / 128, BSD / 128, 1), blk, 0, stream>>>(
      x16, Wkvd16, nullptr, kvkr, BSD, KVPAD, DIMD, 0, 0, 0, KVPAD);
  rmsnorm_k<KVLORA><<<BSD, blk, 0, stream>>>(kvkr, Wkvdb, kvnw, kvlat16, KVPAD);
  gemm_bt<true><<<dim3(4096 / 128, BSD / 128, 1), blk, 0, stream>>>(
      kvlat16, Wkvu16, Wkvub, kvf, BSD, 4096, KVLORA, 0, 0, 0, 4096);
  build_k<<<cdiv((long)BSD * NHD * 96, 256), blk, 0, stream>>>(kvf, kvkr, Wkvdb, freqs, Kh16);
  build_vt<<<dim3(SSD / 32, 128 / 32, BHN), dim3(32, 8), 0, stream>>>(kvf, Vt16);

  // --- balanced fused flash attention: writes O directly in (B,S,NH*128) ---
  flash_attn<<<dim3(8, BHN), dim3(512), 0, stream>>>(Qh16, Kh16, Vt16, attnall);

  // --- output projection (fp32 out) ---
  gemm_bt<false><<<dim3(2048 / 128, BSD / 128, 1), blk, 0, stream>>>(
      attnall, Wo16, Wob, out, BSD, DIMD, 2048, 0, 0, 0, DIMD);
}